// Round 11
// baseline (651.911 us; speedup 1.0000x reference)
//
#include <hip/hip_runtime.h>

// Round 11 = round-10 A/B/C/D probe, resubmitted verbatim (broker timeouts;
// never executed). Per-dispatch rocprof rows = 4 experiments in one bench:
// C = gather floor (1q/thr), D = gather w/ 4-way MLP (latency remedy),
// B = MFMA structure timing, A = validated pk-fp32 output.
#define HW_DIM 1024
#define LATD   32
#define HIDD   64

typedef float v4f   __attribute__((ext_vector_type(4)));
typedef short bf16x8 __attribute__((ext_vector_type(8)));
typedef float f32x4 __attribute__((ext_vector_type(4)));

// ===========================================================================
// Dispatch 0 (tiny): truncation-cast W1/W2 fp32 -> bf16 into d_ws.
// ===========================================================================
__global__ __launch_bounds__(256) void cvt_weights_kernel(
    const float* __restrict__ W1, const float* __restrict__ W2,
    unsigned short* __restrict__ w1bf, unsigned short* __restrict__ w2bf)
{
    const int t = blockIdx.x * blockDim.x + threadIdx.x;
    if (t < 2048) {
        w1bf[t] = (unsigned short)(__builtin_bit_cast(unsigned, W1[t]) >> 16);
    } else if (t < 6144) {
        const int t2 = t - 2048;
        w2bf[t2] = (unsigned short)(__builtin_bit_cast(unsigned, W2[t2]) >> 16);
    }
}

// ===========================================================================
// Dispatch 1: variant C -- GATHER-ONLY PROBE (1 query/thread).
// Memory-side floor. No global writes; asm keep-alive prevents DCE.
// ===========================================================================
__global__ __launch_bounds__(256) void gather_probe_kernel(
    const int2*   __restrict__ queries,
    const int4*   __restrict__ neighbor_map,
    const float2* __restrict__ positions,
    const v4f*    __restrict__ embeddings,
    int B)
{
    const int tid = blockIdx.x * blockDim.x + threadIdx.x;
    if (tid >= B) return;

    const int2 q  = queries[tid];
    const int4 nb = neighbor_map[q.x * HW_DIM + q.y];
    const float qx = (float)q.x, qy = (float)q.y;
    const float2 p0 = positions[nb.x], p1 = positions[nb.y];
    const float2 p2 = positions[nb.z], p3 = positions[nb.w];
    const float d0 = sqrtf((p0.x-qx)*(p0.x-qx) + (p0.y-qy)*(p0.y-qy));
    const float d1 = sqrtf((p1.x-qx)*(p1.x-qx) + (p1.y-qy)*(p1.y-qy));
    const float d2 = sqrtf((p2.x-qx)*(p2.x-qx) + (p2.y-qy)*(p2.y-qy));
    const float d3 = sqrtf((p3.x-qx)*(p3.x-qx) + (p3.y-qy)*(p3.y-qy));

    const v4f* e0 = embeddings + nb.x * 8;
    const v4f* e1 = embeddings + nb.y * 8;
    const v4f* e2 = embeddings + nb.z * 8;
    const v4f* e3 = embeddings + nb.w * 8;
    v4f s = {0, 0, 0, 0};
#pragma unroll
    for (int c = 0; c < 8; ++c)
        s += (e0[c]*d0 + e1[c]*d1) + (e2[c]*d2 + e3[c]*d3);

    asm volatile("" :: "v"(s.x), "v"(s.y), "v"(s.z), "v"(s.w));
}

// ===========================================================================
// Dispatch 2: variant D -- GATHER PROBE, 4 queries/thread (4 independent
// load chains -> memory-level parallelism). Tests the latency remedy.
// ===========================================================================
__global__ __launch_bounds__(256) void gather_probe4_kernel(
    const int2*   __restrict__ queries,
    const int4*   __restrict__ neighbor_map,
    const float2* __restrict__ positions,
    const v4f*    __restrict__ embeddings,
    int B)
{
    const int nthreads = (B >> 2);
    const int tid = blockIdx.x * blockDim.x + threadIdx.x;
    if (tid >= nthreads) return;

    v4f s = {0, 0, 0, 0};
#pragma unroll
    for (int k = 0; k < 4; ++k) {
        const int idx = tid + k * nthreads;       // coalesced per-k
        const int2 q  = queries[idx];
        const int4 nb = neighbor_map[q.x * HW_DIM + q.y];
        const float qx = (float)q.x, qy = (float)q.y;
        const float2 p0 = positions[nb.x], p1 = positions[nb.y];
        const float2 p2 = positions[nb.z], p3 = positions[nb.w];
        const float d0 = sqrtf((p0.x-qx)*(p0.x-qx) + (p0.y-qy)*(p0.y-qy));
        const float d1 = sqrtf((p1.x-qx)*(p1.x-qx) + (p1.y-qy)*(p1.y-qy));
        const float d2 = sqrtf((p2.x-qx)*(p2.x-qx) + (p2.y-qy)*(p2.y-qy));
        const float d3 = sqrtf((p3.x-qx)*(p3.x-qx) + (p3.y-qy)*(p3.y-qy));

        const v4f* e0 = embeddings + nb.x * 8;
        const v4f* e1 = embeddings + nb.y * 8;
        const v4f* e2 = embeddings + nb.z * 8;
        const v4f* e3 = embeddings + nb.w * 8;
#pragma unroll
        for (int c = 0; c < 8; ++c)
            s += (e0[c]*d0 + e1[c]*d1) + (e2[c]*d2 + e3[c]*d3);
    }
    asm volatile("" :: "v"(s.x), "v"(s.y), "v"(s.z), "v"(s.w));
}

// ===========================================================================
// Dispatch 3: variant B -- MFMA TIMING PROBE. No global writes (keep-alive).
// gather+latent -> bf16 LDS A-tile [64q x 32] -> 16x MFMA layer1 ->
// LDS h-tile [64q x 64] -> 32x MFMA layer2 -> scalar layer 3.
// ===========================================================================
__global__ __launch_bounds__(256) void mfma_probe_kernel(
    const int2*   __restrict__ queries,
    const int4*   __restrict__ neighbor_map,
    const float2* __restrict__ positions,
    const v4f*    __restrict__ embeddings,
    const unsigned short* __restrict__ w1bf,   // 64x32 bf16 row-major
    const float*  __restrict__ b1,
    const unsigned short* __restrict__ w2bf,   // 64x64 bf16 row-major
    const float*  __restrict__ b2,
    const float*  __restrict__ W3,
    const float*  __restrict__ b3,
    int B)
{
#pragma clang fp contract(fast)
    __shared__ unsigned short lds[4][2048 + 4096];
    const int w = threadIdx.x >> 6;
    const int l = threadIdx.x & 63;
    unsigned short* latA = &lds[w][0];
    unsigned short* hT   = &lds[w][2048];

    const int tid = blockIdx.x * blockDim.x + threadIdx.x;

    // ---- phase 1: gather + latent ----
    const int2 q  = queries[tid];
    const int4 nb = neighbor_map[q.x * HW_DIM + q.y];
    const float qx = (float)q.x, qy = (float)q.y;
    const float2 p0 = positions[nb.x], p1 = positions[nb.y];
    const float2 p2 = positions[nb.z], p3 = positions[nb.w];
    const float d0 = sqrtf((p0.x-qx)*(p0.x-qx) + (p0.y-qy)*(p0.y-qy));
    const float d1 = sqrtf((p1.x-qx)*(p1.x-qx) + (p1.y-qy)*(p1.y-qy));
    const float d2 = sqrtf((p2.x-qx)*(p2.x-qx) + (p2.y-qy)*(p2.y-qy));
    const float d3 = sqrtf((p3.x-qx)*(p3.x-qx) + (p3.y-qy)*(p3.y-qy));

    const v4f* e0 = embeddings + nb.x * 8;
    const v4f* e1 = embeddings + nb.y * 8;
    const v4f* e2 = embeddings + nb.z * 8;
    const v4f* e3 = embeddings + nb.w * 8;
    v4f lat[8];
#pragma unroll
    for (int c = 0; c < 8; ++c)
        lat[c] = (e0[c]*d0 + e1[c]*d1) + (e2[c]*d2 + e3[c]*d3);

    unsigned lu[8];
#pragma unroll
    for (int c = 0; c < 8; ++c) {
        lu[2*c]   = (__builtin_bit_cast(unsigned, lat[c].y) & 0xffff0000u) |
                    (__builtin_bit_cast(unsigned, lat[c].x) >> 16);
        lu[2*c+1] = (__builtin_bit_cast(unsigned, lat[c].w) & 0xffff0000u) |
                    (__builtin_bit_cast(unsigned, lat[c].z) >> 16);
    }
    unsigned* lrow = (unsigned*)(latA + l * 32);
#pragma unroll
    for (int i = 0; i < 8; ++i) lrow[i] = lu[i];
    __syncthreads();

    // ---- phase 2: layer 1 via 16 MFMA ----
    const int r16 = l & 15;
    const int g4  = l >> 4;
    f32x4 acc1[4][4];
#pragma unroll
    for (int m = 0; m < 4; ++m)
#pragma unroll
        for (int n = 0; n < 4; ++n) acc1[m][n] = (f32x4){0,0,0,0};

    bf16x8 af[4];
#pragma unroll
    for (int m = 0; m < 4; ++m)
        af[m] = *(const bf16x8*)(latA + (m*16 + r16)*32 + g4*8);
#pragma unroll
    for (int n = 0; n < 4; ++n) {
        const bf16x8 bf = *(const bf16x8*)(w1bf + (n*16 + r16)*32 + g4*8);
#pragma unroll
        for (int m = 0; m < 4; ++m)
            acc1[m][n] = __builtin_amdgcn_mfma_f32_16x16x32_bf16(af[m], bf, acc1[m][n], 0, 0, 0);
    }

    float b1j[4];
#pragma unroll
    for (int n = 0; n < 4; ++n) b1j[n] = b1[n*16 + r16];
#pragma unroll
    for (int m = 0; m < 4; ++m)
#pragma unroll
        for (int n = 0; n < 4; ++n)
#pragma unroll
            for (int r = 0; r < 4; ++r) {
                const int qq = m*16 + g4*4 + r;
                const float v = fmaxf(acc1[m][n][r] + b1j[n], 0.0f);
                hT[qq*64 + n*16 + r16] =
                    (unsigned short)(__builtin_bit_cast(unsigned, v) >> 16);
            }
    __syncthreads();

    // ---- phase 3: layer 2 via 32 MFMA ----
    f32x4 acc2[4][4];
#pragma unroll
    for (int m = 0; m < 4; ++m)
#pragma unroll
        for (int n = 0; n < 4; ++n) acc2[m][n] = (f32x4){0,0,0,0};
#pragma unroll
    for (int step = 0; step < 2; ++step) {
        bf16x8 a2[4];
#pragma unroll
        for (int m = 0; m < 4; ++m)
            a2[m] = *(const bf16x8*)(hT + (m*16 + r16)*64 + step*32 + g4*8);
#pragma unroll
        for (int n = 0; n < 4; ++n) {
            const bf16x8 bf = *(const bf16x8*)(w2bf + (n*16 + r16)*64 + step*32 + g4*8);
#pragma unroll
            for (int m = 0; m < 4; ++m)
                acc2[m][n] = __builtin_amdgcn_mfma_f32_16x16x32_bf16(a2[m], bf, acc2[m][n], 0, 0, 0);
        }
    }
    __syncthreads();

    float b2j[4];
#pragma unroll
    for (int n = 0; n < 4; ++n) b2j[n] = b2[n*16 + r16];
#pragma unroll
    for (int m = 0; m < 4; ++m)
#pragma unroll
        for (int n = 0; n < 4; ++n)
#pragma unroll
            for (int r = 0; r < 4; ++r) {
                const int qq = m*16 + g4*4 + r;
                const float v = fmaxf(acc2[m][n][r] + b2j[n], 0.0f);
                hT[qq*64 + n*16 + r16] =
                    (unsigned short)(__builtin_bit_cast(unsigned, v) >> 16);
            }
    __syncthreads();

    // ---- phase 4: layer 3 per-thread ----
    float o0 = b3[0], o1 = b3[1], o2 = b3[2];
#pragma unroll
    for (int u = 0; u < 8; ++u) {
        const bf16x8 hv = *(const bf16x8*)(hT + l*64 + u*8);
#pragma unroll
        for (int e = 0; e < 8; ++e) {
            const float f = __builtin_bit_cast(float,
                (unsigned)((unsigned short)hv[e]) << 16);
            const int j = u*8 + e;
            o0 = fmaf(f, W3[0*HIDD + j], o0);
            o1 = fmaf(f, W3[1*HIDD + j], o1);
            o2 = fmaf(f, W3[2*HIDD + j], o2);
        }
    }
    asm volatile("" :: "v"(o0), "v"(o1), "v"(o2));
}

// ===========================================================================
// Dispatch 4: variant A -- validated pk-fp32 kernel (I$-resident ~14 KB).
// ===========================================================================
__global__ __launch_bounds__(256) void fused_model_kernel(
    const int2*   __restrict__ queries,
    const int4*   __restrict__ neighbor_map,
    const float2* __restrict__ positions,
    const v4f*    __restrict__ embeddings,
    const float*  __restrict__ W1,
    const float*  __restrict__ b1,
    const float*  __restrict__ W2,
    const float*  __restrict__ b2,
    const float*  __restrict__ W3,
    const float*  __restrict__ b3,
    const float*  __restrict__ mu,
    const float*  __restrict__ sd,
    float*        __restrict__ out,
    int B)
{
#pragma clang fp contract(fast)
    const int tid = blockIdx.x * blockDim.x + threadIdx.x;
    if (tid >= B) return;

    const int2 q  = queries[tid];
    const int4 nb = neighbor_map[q.x * HW_DIM + q.y];
    const float qx = (float)q.x, qy = (float)q.y;

    const float2 p0 = positions[nb.x], p1 = positions[nb.y];
    const float2 p2 = positions[nb.z], p3 = positions[nb.w];
    const float d0 = sqrtf((p0.x-qx)*(p0.x-qx) + (p0.y-qy)*(p0.y-qy));
    const float d1 = sqrtf((p1.x-qx)*(p1.x-qx) + (p1.y-qy)*(p1.y-qy));
    const float d2 = sqrtf((p2.x-qx)*(p2.x-qx) + (p2.y-qy)*(p2.y-qy));
    const float d3 = sqrtf((p3.x-qx)*(p3.x-qx) + (p3.y-qy)*(p3.y-qy));

    const v4f* e0 = embeddings + nb.x * 8;
    const v4f* e1 = embeddings + nb.y * 8;
    const v4f* e2 = embeddings + nb.z * 8;
    const v4f* e3 = embeddings + nb.w * 8;
    v4f lat[8];
#pragma unroll
    for (int c = 0; c < 8; ++c)
        lat[c] = (e0[c]*d0 + e1[c]*d1) + (e2[c]*d2 + e3[c]*d3);

    v4f h1[16];
#pragma unroll
    for (int j = 0; j < HIDD; ++j) {
        const v4f* wr = (const v4f*)(W1 + j * LATD);
        v4f aA = wr[0] * lat[0];
        v4f aB = wr[1] * lat[1];
#pragma unroll
        for (int ll = 2; ll < 8; ll += 2) {
            aA += wr[ll]     * lat[ll];
            aB += wr[ll + 1] * lat[ll + 1];
        }
        const v4f a = aA + aB;
        const float t = ((a.x + a.y) + (a.z + a.w)) + b1[j];
        h1[j >> 2][j & 3] = fmaxf(t, 0.0f);
    }

    float o0 = b3[0], o1 = b3[1], o2 = b3[2];
#pragma unroll 4
    for (int j = 0; j < HIDD; ++j) {
        const v4f* wr = (const v4f*)(W2 + j * HIDD);
        v4f aA = wr[0] * h1[0];
        v4f aB = wr[1] * h1[1];
#pragma unroll
        for (int ll = 2; ll < 16; ll += 2) {
            aA += wr[ll]     * h1[ll];
            aB += wr[ll + 1] * h1[ll + 1];
        }
        const v4f a = aA + aB;
        const float t = fmaxf(((a.x + a.y) + (a.z + a.w)) + b2[j], 0.0f);
        o0 = fmaf(W3[0*HIDD + j], t, o0);
        o1 = fmaf(W3[1*HIDD + j], t, o1);
        o2 = fmaf(W3[2*HIDD + j], t, o2);
    }

    const float r0 = fminf(fmaxf(fmaf(o0, sd[0], mu[0]), 0.0f), 1.0f);
    const float r1 = fminf(fmaxf(fmaf(o1, sd[1], mu[1]), 0.0f), 1.0f);
    const float r2 = fminf(fmaxf(fmaf(o2, sd[2], mu[2]), 0.0f), 1.0f);
    out[tid*3 + 0] = r0;
    out[tid*3 + 1] = r1;
    out[tid*3 + 2] = r2;
}

extern "C" void kernel_launch(void* const* d_in, const int* in_sizes, int n_in,
                              void* d_out, int out_size, void* d_ws, size_t ws_size,
                              hipStream_t stream) {
    const int2*   queries      = (const int2*)d_in[0];
    const int4*   neighbor_map = (const int4*)d_in[1];
    const float2* positions    = (const float2*)d_in[2];
    const v4f*    embeddings   = (const v4f*)d_in[3];
    const float*  W1 = (const float*)d_in[4];
    const float*  b1 = (const float*)d_in[5];
    const float*  W2 = (const float*)d_in[6];
    const float*  b2 = (const float*)d_in[7];
    const float*  W3 = (const float*)d_in[8];
    const float*  b3 = (const float*)d_in[9];
    const float*  mu = (const float*)d_in[10];
    const float*  sd = (const float*)d_in[11];
    float* out = (float*)d_out;

    const int B = in_sizes[0] / 2;

    unsigned short* w1bf = (unsigned short*)d_ws;
    unsigned short* w2bf = w1bf + 2048;

    cvt_weights_kernel<<<24, 256, 0, stream>>>(W1, W2, w1bf, w2bf);

    // Variant C: gather-only floor probe (1 query/thread, no global writes).
    gather_probe_kernel<<<(B + 255) / 256, 256, 0, stream>>>(
        queries, neighbor_map, positions, embeddings, B);

    // Variant D: gather probe, 4 queries/thread (latency-hiding remedy test).
    gather_probe4_kernel<<<(B / 4 + 255) / 256, 256, 0, stream>>>(
        queries, neighbor_map, positions, embeddings, B);

    // Variant B: MFMA timing probe (no global writes).
    mfma_probe_kernel<<<B / 256, 256, 0, stream>>>(
        queries, neighbor_map, positions, embeddings,
        w1bf, b1, w2bf, b2, W3, b3, B);

    // Variant A: validated output.
    fused_model_kernel<<<(B + 255) / 256, 256, 0, stream>>>(
        queries, neighbor_map, positions, embeddings,
        W1, b1, W2, b2, W3, b3, mu, sd, out, B);
}

// Round 13
// 270.313 us; speedup vs baseline: 2.4117x; 2.4117x over previous
//
#include <hip/hip_runtime.h>

// Round 13 = round-12 fused MFMA kernel, resubmitted verbatim after re-audit
// (broker timeout; never executed). One wave = 32 queries.
// LDS (per wave, 8 KB, reused): gather partials [2][32][32]f32 ->
// h1 [32][64]f32 -> h2 [32][64]f32. XOR-swizzle ((row&7)<<4) on all rows.
// bf16x3: x = hi + lo (bf16 each); x*w ~ xh*wh + xl*wh + xh*wl (rel err ~2^-16).
#define HW_DIM 1024

typedef float v4f   __attribute__((ext_vector_type(4)));
typedef float f32x4 __attribute__((ext_vector_type(4)));
typedef short bf16x8 __attribute__((ext_vector_type(8)));
typedef unsigned int u32x4 __attribute__((ext_vector_type(4)));

__device__ __forceinline__ unsigned bf_rne(float x) {
    unsigned u = __builtin_bit_cast(unsigned, x);
    return (u + 0x7fffu + ((u >> 16) & 1u)) >> 16;   // round-to-nearest-even bf16
}
__device__ __forceinline__ float bf_to_f(unsigned hbits) {
    return __builtin_bit_cast(float, hbits << 16);
}
// split 8 f32 into hi/lo bf16x8 MFMA operands
__device__ __forceinline__ void split8(const float* a, bf16x8* ah, bf16x8* al) {
    u32x4 vh, vl;
#pragma unroll
    for (int i = 0; i < 4; ++i) {
        const unsigned h0 = bf_rne(a[2*i]);
        const unsigned h1 = bf_rne(a[2*i+1]);
        vh[i] = h0 | (h1 << 16);
        const float l0 = a[2*i]   - bf_to_f(h0);
        const float l1 = a[2*i+1] - bf_to_f(h1);
        vl[i] = bf_rne(l0) | (bf_rne(l1) << 16);
    }
    *ah = __builtin_bit_cast(bf16x8, vh);
    *al = __builtin_bit_cast(bf16x8, vl);
}

// ---------------------------------------------------------------------------
// Tiny pre-kernel: hi/lo bf16 split of W1 (64x32) and W2 (64x64) into d_ws.
// ---------------------------------------------------------------------------
__global__ __launch_bounds__(256) void split_weights_kernel(
    const float* __restrict__ W1, const float* __restrict__ W2,
    unsigned short* __restrict__ w1h, unsigned short* __restrict__ w1l,
    unsigned short* __restrict__ w2h, unsigned short* __restrict__ w2l)
{
    const int t = blockIdx.x * blockDim.x + threadIdx.x;
    if (t < 2048) {
        const float x = W1[t];
        const unsigned h = bf_rne(x);
        w1h[t] = (unsigned short)h;
        w1l[t] = (unsigned short)bf_rne(x - bf_to_f(h));
    } else if (t < 6144) {
        const int t2 = t - 2048;
        const float x = W2[t2];
        const unsigned h = bf_rne(x);
        w2h[t2] = (unsigned short)h;
        w2l[t2] = (unsigned short)bf_rne(x - bf_to_f(h));
    }
}

// ---------------------------------------------------------------------------
// Main kernel. 256 threads = 4 waves; wave handles 32 consecutive queries.
// ---------------------------------------------------------------------------
__global__ __launch_bounds__(256) void fused_mfma_kernel(
    const int2*   __restrict__ queries,
    const int2*   __restrict__ nbmap2,      // neighbor_map as int2 pairs
    const float2* __restrict__ positions,
    const v4f*    __restrict__ embeddings,  // N x 8 v4f
    const unsigned short* __restrict__ w1h,
    const unsigned short* __restrict__ w1l,
    const unsigned short* __restrict__ w2h,
    const unsigned short* __restrict__ w2l,
    const float*  __restrict__ b1,
    const float*  __restrict__ b2,
    const float*  __restrict__ W3,          // 3x64 row-major (wave-uniform)
    const float*  __restrict__ b3,
    const float*  __restrict__ mu,
    const float*  __restrict__ sd,
    float*        __restrict__ out)
{
#pragma clang fp contract(fast)
    __shared__ char smem[4][8192];
    const int l  = threadIdx.x & 63;
    const int w  = threadIdx.x >> 6;
    char* s = smem[w];                       // wave-private 8 KB
    const int qb = (blockIdx.x * 4 + w) * 32;

    // ---- phase 1: gather, 2 lanes per query (one neighbor-pair each) ----
    const int qr = l >> 1;                   // query row 0..31
    const int hh = l & 1;                    // neighbor-pair half
    const int2 q2 = queries[qb + qr];
    const int2 nb = nbmap2[(q2.x * HW_DIM + q2.y) * 2 + hh];
    const float qx = (float)q2.x, qy = (float)q2.y;
    const float2 pa = positions[nb.x];
    const float2 pb = positions[nb.y];
    const float da = sqrtf((pa.x-qx)*(pa.x-qx) + (pa.y-qy)*(pa.y-qy));
    const float db = sqrtf((pb.x-qx)*(pb.x-qx) + (pb.y-qy)*(pb.y-qy));
    const v4f* ea = embeddings + nb.x * 8;
    const v4f* eb = embeddings + nb.y * 8;
    {
        const int rb = hh * 4096 + qr * 128;
        const int sw = (qr & 7) << 4;
#pragma unroll
        for (int i = 0; i < 8; ++i) {
            const v4f p = ea[i] * da + eb[i] * db;      // f32 partial latent
            *(v4f*)(s + ((rb + i*16) ^ sw)) = p;
        }
    }
    __syncthreads();

    const int r16 = l & 15;
    const int g4  = l >> 4;

    // ---- phase 2: layer 1 [32q x 32k] x W1^T -> h1[32q x 64], bf16x3 ----
    bf16x8 a1h[2], a1l[2];
#pragma unroll
    for (int m = 0; m < 2; ++m) {            // A-frag: row = m*16+r16, k = g4*8+j
        const int row = m*16 + r16;
        const int sw  = (row & 7) << 4;
        float av[8];
#pragma unroll
        for (int t = 0; t < 2; ++t) {
            const v4f p0 = *(const v4f*)(s + ((       row*128 + g4*32 + t*16) ^ sw));
            const v4f p1 = *(const v4f*)(s + ((4096 + row*128 + g4*32 + t*16) ^ sw));
#pragma unroll
            for (int j = 0; j < 4; ++j) av[t*4+j] = p0[j] + p1[j];  // sum halves
        }
        split8(av, &a1h[m], &a1l[m]);
    }

    f32x4 acc1[2][4];
#pragma unroll
    for (int m = 0; m < 2; ++m)
#pragma unroll
        for (int n = 0; n < 4; ++n) acc1[m][n] = (f32x4){0.f,0.f,0.f,0.f};

#pragma unroll
    for (int n = 0; n < 4; ++n) {            // B-frag: col=r16, k=g4*8+j
        const bf16x8 bh = *(const bf16x8*)(w1h + (n*16 + r16)*32 + g4*8);
        const bf16x8 bl = *(const bf16x8*)(w1l + (n*16 + r16)*32 + g4*8);
#pragma unroll
        for (int m = 0; m < 2; ++m) {
            acc1[m][n] = __builtin_amdgcn_mfma_f32_16x16x32_bf16(a1h[m], bh, acc1[m][n],0,0,0);
            acc1[m][n] = __builtin_amdgcn_mfma_f32_16x16x32_bf16(a1l[m], bh, acc1[m][n],0,0,0);
            acc1[m][n] = __builtin_amdgcn_mfma_f32_16x16x32_bf16(a1h[m], bl, acc1[m][n],0,0,0);
        }
    }

    // h1 = relu(acc1 + b1) -> LDS f32 [32][256B rows] (overwrites partials;
    // same-wave LDS ops execute in program order; buffers wave-private)
    float b1v[4];
#pragma unroll
    for (int n = 0; n < 4; ++n) b1v[n] = b1[n*16 + r16];
#pragma unroll
    for (int m = 0; m < 2; ++m)
#pragma unroll
        for (int n = 0; n < 4; ++n)
#pragma unroll
            for (int r = 0; r < 4; ++r) {
                const int row = m*16 + g4*4 + r;       // C: row=(lane>>4)*4+reg
                const int col = n*16 + r16;            //    col=lane&15  [m89]
                const float v = fmaxf(acc1[m][n][r] + b1v[n], 0.0f);
                *(float*)(s + ((row*256 + col*4) ^ ((row&7)<<4))) = v;
            }
    __syncthreads();

    // ---- phase 3: layer 2 [32q x 64k] x W2^T -> h2[32q x 64], bf16x3 ----
    f32x4 acc2[2][4];
#pragma unroll
    for (int m = 0; m < 2; ++m)
#pragma unroll
        for (int n = 0; n < 4; ++n) acc2[m][n] = (f32x4){0.f,0.f,0.f,0.f};

#pragma unroll
    for (int ks = 0; ks < 2; ++ks) {
        bf16x8 a2h[2], a2l[2];
#pragma unroll
        for (int m = 0; m < 2; ++m) {
            const int row = m*16 + r16;
            const int sw  = (row & 7) << 4;
            float av[8];
#pragma unroll
            for (int t = 0; t < 2; ++t) {
                const v4f p = *(const v4f*)(s + ((row*256 + ks*128 + g4*32 + t*16) ^ sw));
#pragma unroll
                for (int j = 0; j < 4; ++j) av[t*4+j] = p[j];
            }
            split8(av, &a2h[m], &a2l[m]);
        }
#pragma unroll
        for (int n = 0; n < 4; ++n) {
            const bf16x8 bh = *(const bf16x8*)(w2h + (n*16 + r16)*64 + ks*32 + g4*8);
            const bf16x8 bl = *(const bf16x8*)(w2l + (n*16 + r16)*64 + ks*32 + g4*8);
#pragma unroll
            for (int m = 0; m < 2; ++m) {
                acc2[m][n] = __builtin_amdgcn_mfma_f32_16x16x32_bf16(a2h[m], bh, acc2[m][n],0,0,0);
                acc2[m][n] = __builtin_amdgcn_mfma_f32_16x16x32_bf16(a2l[m], bh, acc2[m][n],0,0,0);
                acc2[m][n] = __builtin_amdgcn_mfma_f32_16x16x32_bf16(a2h[m], bl, acc2[m][n],0,0,0);
            }
        }
    }

    // h2 = relu(acc2 + b2) -> LDS (overwrites h1; h1 reads complete)
    float b2v[4];
#pragma unroll
    for (int n = 0; n < 4; ++n) b2v[n] = b2[n*16 + r16];
#pragma unroll
    for (int m = 0; m < 2; ++m)
#pragma unroll
        for (int n = 0; n < 4; ++n)
#pragma unroll
            for (int r = 0; r < 4; ++r) {
                const int row = m*16 + g4*4 + r;
                const int col = n*16 + r16;
                const float v = fmaxf(acc2[m][n][r] + b2v[n], 0.0f);
                *(float*)(s + ((row*256 + col*4) ^ ((row&7)<<4))) = v;
            }
    __syncthreads();

    // ---- phase 4: layer 3 + affine + clip, 1 query per lane (lanes 0..31) --
    // W3/b3/mu/sd reads are wave-uniform -> scalar path.
    if (l < 32) {
        const int sw = (l & 7) << 4;
        float o0 = b3[0], o1 = b3[1], o2 = b3[2];
#pragma unroll
        for (int i = 0; i < 16; ++i) {
            const v4f hv = *(const v4f*)(s + ((l*256 + i*16) ^ sw));
#pragma unroll
            for (int j = 0; j < 4; ++j) {
                const int n = i*4 + j;
                o0 = fmaf(hv[j], W3[n], o0);
                o1 = fmaf(hv[j], W3[64 + n], o1);
                o2 = fmaf(hv[j], W3[128 + n], o2);
            }
        }
        const int qg = qb + l;
        out[qg*3 + 0] = fminf(fmaxf(fmaf(o0, sd[0], mu[0]), 0.0f), 1.0f);
        out[qg*3 + 1] = fminf(fmaxf(fmaf(o1, sd[1], mu[1]), 0.0f), 1.0f);
        out[qg*3 + 2] = fminf(fmaxf(fmaf(o2, sd[2], mu[2]), 0.0f), 1.0f);
    }
}

extern "C" void kernel_launch(void* const* d_in, const int* in_sizes, int n_in,
                              void* d_out, int out_size, void* d_ws, size_t ws_size,
                              hipStream_t stream) {
    const int2*   queries      = (const int2*)d_in[0];
    const int2*   nbmap2       = (const int2*)d_in[1];
    const float2* positions    = (const float2*)d_in[2];
    const v4f*    embeddings   = (const v4f*)d_in[3];
    const float*  W1 = (const float*)d_in[4];
    const float*  b1 = (const float*)d_in[5];
    const float*  W2 = (const float*)d_in[6];
    const float*  b2 = (const float*)d_in[7];
    const float*  W3 = (const float*)d_in[8];
    const float*  b3 = (const float*)d_in[9];
    const float*  mu = (const float*)d_in[10];
    const float*  sd = (const float*)d_in[11];
    float* out = (float*)d_out;

    const int B = in_sizes[0] / 2;           // queries is B x 2 (B = 2^20)

    // ws: w1h[2048], w1l[2048], w2h[4096], w2l[4096] ushort = 24.6 KB
    unsigned short* w1h = (unsigned short*)d_ws;
    unsigned short* w1l = w1h + 2048;
    unsigned short* w2h = w1l + 2048;
    unsigned short* w2l = w2h + 4096;

    split_weights_kernel<<<24, 256, 0, stream>>>(W1, W2, w1h, w1l, w2h, w2l);

    // 128 queries per block (4 waves x 32). B = 2^20 -> 8192 blocks, no tail.
    fused_mfma_kernel<<<B / 128, 256, 0, stream>>>(
        queries, nbmap2, positions, embeddings,
        w1h, w1l, w2h, w2l, b1, b2, W3, b3, mu, sd, out);
}